// Round 1
// baseline (291.017 us; speedup 1.0000x reference)
//
#include <hip/hip_runtime.h>
#include <cstddef>

// Problem constants (from reference)
constexpr int Bn = 64;     // batch
constexpr int In = 2048;   // input capsules
constexpr int Dk = 8;      // input dim
constexpr int Kc = 16;     // output capsules
constexpr int En = 16;     // output dim
constexpr float EPS = 1e-7f;

// Work decomposition for the iteration kernel
constexpr int BSET = 8;                            // batches per wave
constexpr int IC   = 8;                            // i's per wave
constexpr int NB_GROUPS   = Bn / BSET;             // 8
constexpr int NI_CHUNKS   = In / IC;               // 256
constexpr int TOTAL_WAVES = NB_GROUPS * NI_CHUNKS; // 2048
constexpr int THREADS     = 256;
constexpr int ITER_BLOCKS = TOTAL_WAVES * 64 / THREADS; // 512

// One routing iteration: recompute u_hat on the fly, compute coupling c,
// accumulate s[b,k,e] = sum_i c[b,i,k] * u_hat[b,i,k,e] via global atomics.
// UNIFORM=true  -> c = 1 (the 1/16 scale is applied in the squash kernel)
// UNIFORM=false -> logits t[k] = dot_e(u_hat[k,:], vsum[b,k,:]); c = softmax_k(t)
template<bool UNIFORM>
__global__ __launch_bounds__(256)
void caps_iter(const float* __restrict__ x,     // [B, I, 8]
               const float* __restrict__ W,     // [I, K, 8, E]
               const float* __restrict__ vsum,  // [B, K, E] (sum of previous v's)
               float* __restrict__ s)           // [B, K, E] accumulated (pre-zeroed)
{
    const int gid  = blockIdx.x * blockDim.x + threadIdx.x;
    const int wave = gid >> 6;
    const int lane = threadIdx.x & 63;
    const int g    = wave % NB_GROUPS;        // which batch-group
    const int i0   = (wave / NB_GROUPS) * IC; // first input capsule
    const int k    = lane >> 2;               // output capsule  (0..15)
    const int e4   = (lane & 3) << 2;         // first of 4 output dims

    float4 acc[BSET];
    #pragma unroll
    for (int b = 0; b < BSET; ++b) acc[b] = make_float4(0.f, 0.f, 0.f, 0.f);

    #pragma unroll 1
    for (int ii = 0; ii < IC; ++ii) {
        const int i = i0 + ii;
        // Stage this capsule's W slice in registers: W[i, k, d, e4:e4+4]
        const float* wp = W + (size_t)i * (Kc * Dk * En) + k * (Dk * En) + e4;
        float4 w[8];
        #pragma unroll
        for (int d = 0; d < 8; ++d) w[d] = *(const float4*)(wp + d * En);

        #pragma unroll
        for (int bl = 0; bl < BSET; ++bl) {
            const int b = g * BSET + bl;
            const float* xp = x + ((size_t)b * In + i) * Dk;
            const float4 x0 = *(const float4*)(xp);
            const float4 x1 = *(const float4*)(xp + 4);
            const float xs[8] = {x0.x, x0.y, x0.z, x0.w, x1.x, x1.y, x1.z, x1.w};

            // u_hat[k, e4:e4+4] = sum_d x[d] * W[i,k,d,e4:e4+4]
            float4 uh = make_float4(0.f, 0.f, 0.f, 0.f);
            #pragma unroll
            for (int d = 0; d < 8; ++d) {
                uh.x = fmaf(xs[d], w[d].x, uh.x);
                uh.y = fmaf(xs[d], w[d].y, uh.y);
                uh.z = fmaf(xs[d], w[d].z, uh.z);
                uh.w = fmaf(xs[d], w[d].w, uh.w);
            }

            float c;
            if (UNIFORM) {
                c = 1.0f;   // uniform coupling; 1/16 folded into squash scale
            } else {
                const float4 v = *(const float4*)(vsum + (b * Kc + k) * En + e4);
                float t = uh.x * v.x + uh.y * v.y + uh.z * v.z + uh.w * v.w;
                // reduce over e (4 lanes share k): lanes differ in bits 0..1
                t += __shfl_xor(t, 1);
                t += __shfl_xor(t, 2);
                // softmax over the 16 k's (lane bits 2..5)
                float m = t;
                m = fmaxf(m, __shfl_xor(m, 4));
                m = fmaxf(m, __shfl_xor(m, 8));
                m = fmaxf(m, __shfl_xor(m, 16));
                m = fmaxf(m, __shfl_xor(m, 32));
                const float p = __expf(t - m);
                float den = p;
                den += __shfl_xor(den, 4);
                den += __shfl_xor(den, 8);
                den += __shfl_xor(den, 16);
                den += __shfl_xor(den, 32);
                c = p / den;
            }

            acc[bl].x = fmaf(c, uh.x, acc[bl].x);
            acc[bl].y = fmaf(c, uh.y, acc[bl].y);
            acc[bl].z = fmaf(c, uh.z, acc[bl].z);
            acc[bl].w = fmaf(c, uh.w, acc[bl].w);
        }
    }

    #pragma unroll
    for (int bl = 0; bl < BSET; ++bl) {
        const int b = g * BSET + bl;
        float* sp = s + (b * Kc + k) * En + e4;
        atomicAdd(sp + 0, acc[bl].x);
        atomicAdd(sp + 1, acc[bl].y);
        atomicAdd(sp + 2, acc[bl].z);
        atomicAdd(sp + 3, acc[bl].w);
    }
}

// v = squash(scale * s) [+ vprev]   over axis e (16)
// vprev accumulation builds vsum = v0 + v1 for the last iteration's logits.
__global__ __launch_bounds__(256)
void caps_squash(const float* __restrict__ s, float scale,
                 const float* __restrict__ vprev, float* __restrict__ vout)
{
    const int b = blockIdx.x;       // 0..63
    const int t = threadIdx.x;      // 256 = (k,e)
    const float val = s[b * 256 + t] * scale;
    float sq = val * val;
    // e = t & 15 -> reduce within each 16-lane group
    sq += __shfl_xor(sq, 1);
    sq += __shfl_xor(sq, 2);
    sq += __shfl_xor(sq, 4);
    sq += __shfl_xor(sq, 8);
    const float f = sq / ((1.0f + sq) * sqrtf(sq + EPS));
    float v = val * f;
    if (vprev) v += vprev[b * 256 + t];
    vout[b * 256 + t] = v;
}

extern "C" void kernel_launch(void* const* d_in, const int* in_sizes, int n_in,
                              void* d_out, int out_size, void* d_ws, size_t ws_size,
                              hipStream_t stream) {
    const float* x = (const float*)d_in[0];   // [64, 2048, 8]
    const float* W = (const float*)d_in[1];   // [2048, 16, 8, 16]
    float* out = (float*)d_out;               // [64, 16, 16]
    float* ws  = (float*)d_ws;

    constexpr int SV = Bn * Kc * En;          // 16384 floats
    float* s0 = ws;
    float* s1 = ws + SV;
    float* s2 = ws + 2 * SV;
    float* v0 = ws + 3 * SV;
    float* vs = ws + 4 * SV;

    // zero the three s accumulators (atomically accumulated below)
    hipMemsetAsync(ws, 0, 3 * SV * sizeof(float), stream);

    dim3 blk(THREADS), grid(ITER_BLOCKS);

    // r = 0: uniform coupling
    caps_iter<true><<<grid, blk, 0, stream>>>(x, W, nullptr, s0);
    caps_squash<<<Bn, 256, 0, stream>>>(s0, 1.0f / 16.0f, nullptr, v0);

    // r = 1: logits = dot(u_hat, v0)
    caps_iter<false><<<grid, blk, 0, stream>>>(x, W, v0, s1);
    caps_squash<<<Bn, 256, 0, stream>>>(s1, 1.0f, v0, vs);  // vs = v0 + v1

    // r = 2: logits = dot(u_hat, v0 + v1)
    caps_iter<false><<<grid, blk, 0, stream>>>(x, W, vs, s2);
    caps_squash<<<Bn, 256, 0, stream>>>(s2, 1.0f, nullptr, out);
}

// Round 2
// 117.827 us; speedup vs baseline: 2.4699x; 2.4699x over previous
//
#include <hip/hip_runtime.h>
#include <cstddef>

// Problem constants (from reference)
constexpr int Bn = 64;     // batch
constexpr int In = 2048;   // input capsules
constexpr int Dk = 8;      // input dim
constexpr int Kc = 16;     // output capsules
constexpr int En = 16;     // output dim
constexpr float EPS = 1e-7f;

constexpr int BSET = 8;            // batches per block
constexpr int NBG  = Bn / BSET;    // 8 batch groups
constexpr int NW   = 4;            // waves per block (256 threads)

// One routing iteration, atomic-free.
// Each block: batch-group g (8 batches) x i-chunk p (IB = 4*IC input capsules).
// Waves split the i-chunk; LDS reduction across waves; ONE plain store per
// (block, element) into partial[p][b][k][e]. No atomics -> no HBM RMW traffic.
// UNIFORM=true : c = 1 (the 1/16 is folded into the reduce kernel's scale)
// UNIFORM=false: logits t[k] = dot_e(u_hat[k,:], vsum[b,k,:]); c = softmax_k(t)
template<bool UNIFORM>
__global__ __launch_bounds__(256)
void caps_iter(const float* __restrict__ x,     // [B, I, 8]
               const float* __restrict__ W,     // [I, K, 8, E]
               const float* __restrict__ vsum,  // [B, K, E]
               float* __restrict__ partial,     // [P, B, K, E]
               int IC)                          // i's per wave (4 or 16)
{
    // Region plan (floats):
    //   phase 1: [0 .. 16*IB)  x-stage (<=4096), [4096..6144) vsum-stage
    //   phase 2: [0 .. 8192)   red[4][2048]   (x/vsum dead by then)
    __shared__ float smem[8192];

    const int IB = IC * NW;                 // i's per block
    const int t  = threadIdx.x;
    const int p  = blockIdx.x >> 3;         // i-chunk index
    const int g  = blockIdx.x & 7;          // batch group
    const int i0 = p * IB;

    // ---- stage x[g*8+bl][i0..i0+IB-1][0..7] -> smem flat [bl][il][d] ----
    const int perb = 2 * IB;                // float4 per batch
    const int nf4  = (IB * 16) >> 8;        // float4 per thread
    for (int j = 0; j < nf4; ++j) {
        const int f4 = t + (j << 8);
        const int bl = f4 / perb;
        const int r  = f4 - bl * perb;
        const float4 v = *(const float4*)(x + (((size_t)(g * BSET + bl)) * In + i0) * Dk + r * 4);
        ((float4*)smem)[bl * perb + r] = v;
    }
    // ---- stage vsum[g*8 .. g*8+7][*][*] -> smem + 4096 (2048 floats) ----
    if (!UNIFORM) {
        const float4* vsrc = (const float4*)(vsum + (size_t)g * (BSET * Kc * En));
        ((float4*)(smem + 4096))[t]       = vsrc[t];
        ((float4*)(smem + 4096))[t + 256] = vsrc[t + 256];
    }

    const int lane = t & 63;
    const int wv   = t >> 6;
    const int k    = lane >> 2;             // output capsule
    const int e4   = (lane & 3) << 2;       // first of 4 output dims

    __syncthreads();

    float4 acc[BSET];
    #pragma unroll
    for (int bl = 0; bl < BSET; ++bl) acc[bl] = make_float4(0.f, 0.f, 0.f, 0.f);

    #pragma unroll 1
    for (int ii = 0; ii < IC; ++ii) {
        const int il = wv * IC + ii;
        const int i  = i0 + il;
        // W[i, k, d, e4:e4+4] staged in registers
        const float* wp = W + (size_t)i * (Kc * Dk * En) + k * (Dk * En) + e4;
        float4 w[8];
        #pragma unroll
        for (int d = 0; d < 8; ++d) w[d] = *(const float4*)(wp + d * En);

        #pragma unroll
        for (int bl = 0; bl < BSET; ++bl) {
            const float* xp = smem + ((bl * IB + il) << 3);   // broadcast reads
            const float4 x0 = *(const float4*)xp;
            const float4 x1 = *(const float4*)(xp + 4);
            const float xs8[8] = {x0.x, x0.y, x0.z, x0.w, x1.x, x1.y, x1.z, x1.w};

            float4 uh = make_float4(0.f, 0.f, 0.f, 0.f);
            #pragma unroll
            for (int d = 0; d < 8; ++d) {
                uh.x = fmaf(xs8[d], w[d].x, uh.x);
                uh.y = fmaf(xs8[d], w[d].y, uh.y);
                uh.z = fmaf(xs8[d], w[d].z, uh.z);
                uh.w = fmaf(xs8[d], w[d].w, uh.w);
            }

            if (UNIFORM) {
                acc[bl].x += uh.x; acc[bl].y += uh.y;
                acc[bl].z += uh.z; acc[bl].w += uh.w;
            } else {
                const float4 vb = *(const float4*)(smem + 4096 + (bl << 8) + k * 16 + e4);
                float tt = uh.x * vb.x + uh.y * vb.y + uh.z * vb.z + uh.w * vb.w;
                tt += __shfl_xor(tt, 1);          // reduce over e (lane bits 0..1)
                tt += __shfl_xor(tt, 2);
                float m = tt;                      // softmax over k (lane bits 2..5)
                m = fmaxf(m, __shfl_xor(m, 4));
                m = fmaxf(m, __shfl_xor(m, 8));
                m = fmaxf(m, __shfl_xor(m, 16));
                m = fmaxf(m, __shfl_xor(m, 32));
                const float pe = __expf(tt - m);
                float den = pe;
                den += __shfl_xor(den, 4);
                den += __shfl_xor(den, 8);
                den += __shfl_xor(den, 16);
                den += __shfl_xor(den, 32);
                const float c = pe / den;
                acc[bl].x = fmaf(c, uh.x, acc[bl].x);
                acc[bl].y = fmaf(c, uh.y, acc[bl].y);
                acc[bl].z = fmaf(c, uh.z, acc[bl].z);
                acc[bl].w = fmaf(c, uh.w, acc[bl].w);
            }
        }
    }

    // ---- cross-wave LDS reduction, then one plain store per element ----
    __syncthreads();                                  // x/vsum stages dead
    {
        float* slab = smem + (wv << 11);              // red[wv][2048]
        #pragma unroll
        for (int bl = 0; bl < BSET; ++bl)
            *(float4*)(slab + (bl << 8) + k * 16 + e4) = acc[bl];
    }
    __syncthreads();
    const size_t pb = ((size_t)p * Bn + g * BSET) * 256;
    #pragma unroll
    for (int j = 0; j < BSET; ++j) {
        const int idx = (j << 8) + t;
        const float s = smem[idx] + smem[2048 + idx] + smem[4096 + idx] + smem[6144 + idx];
        partial[pb + (size_t)(j << 8) + t] = s;
    }
}

// Sum the P partials, then v = squash(scale * s) [+ vprev].
__global__ __launch_bounds__(256)
void caps_reduce(const float* __restrict__ partial, int P, float scale,
                 const float* __restrict__ vprev, float* __restrict__ vout)
{
    const int b = blockIdx.x;       // 0..63
    const int t = threadIdx.x;      // (k,e)
    const float* pp = partial + (size_t)b * 256 + t;
    const size_t st = (size_t)Bn * 256;
    float s0 = 0.f, s1 = 0.f, s2 = 0.f, s3 = 0.f;
    for (int p = 0; p < P; p += 4) {
        s0 += pp[(size_t)p * st];
        s1 += pp[(size_t)(p + 1) * st];
        s2 += pp[(size_t)(p + 2) * st];
        s3 += pp[(size_t)(p + 3) * st];
    }
    const float val = ((s0 + s1) + (s2 + s3)) * scale;
    float sq = val * val;
    sq += __shfl_xor(sq, 1);        // e = t & 15 -> within-16 reduction
    sq += __shfl_xor(sq, 2);
    sq += __shfl_xor(sq, 4);
    sq += __shfl_xor(sq, 8);
    const float f = sq / ((1.0f + sq) * sqrtf(sq + EPS));
    float v = val * f;
    if (vprev) v += vprev[b * 256 + t];
    vout[b * 256 + t] = v;
}

extern "C" void kernel_launch(void* const* d_in, const int* in_sizes, int n_in,
                              void* d_out, int out_size, void* d_ws, size_t ws_size,
                              hipStream_t stream) {
    const float* x = (const float*)d_in[0];   // [64, 2048, 8]
    const float* W = (const float*)d_in[1];   // [2048, 16, 8, 16]
    float* out = (float*)d_out;               // [64, 16, 16]
    float* ws  = (float*)d_ws;

    float* v0      = ws;                      // [64,16,16]
    float* vs      = ws + 16384;              // v0 + v1
    float* partial = ws + 32768;              // [P, 64, 16, 16]

    int IC = 4, P = 128;                      // 1024 blocks, 8.125 MB ws
    if (ws_size < (32768 + (size_t)128 * Bn * 256) * sizeof(float)) {
        IC = 16; P = 32;                      // 2.125 MB fallback
    }

    dim3 blk(256);

    // r = 0: uniform coupling (1/16 folded into reduce scale)
    caps_iter<true ><<<P * NBG, blk, 0, stream>>>(x, W, nullptr, partial, IC);
    caps_reduce<<<Bn, blk, 0, stream>>>(partial, P, 1.0f / 16.0f, nullptr, v0);

    // r = 1: logits = dot(u_hat, v0);  vs = v0 + v1
    caps_iter<false><<<P * NBG, blk, 0, stream>>>(x, W, v0, partial, IC);
    caps_reduce<<<Bn, blk, 0, stream>>>(partial, P, 1.0f, v0, vs);

    // r = 2: logits = dot(u_hat, v0 + v1)
    caps_iter<false><<<P * NBG, blk, 0, stream>>>(x, W, vs, partial, IC);
    caps_reduce<<<Bn, blk, 0, stream>>>(partial, P, 1.0f, nullptr, out);
}

// Round 3
// 87.796 us; speedup vs baseline: 3.3147x; 1.3420x over previous
//
#include <hip/hip_runtime.h>
#include <cstddef>

// Problem constants (from reference)
constexpr int Bn = 64;     // batch
constexpr int In = 2048;   // input capsules
constexpr int Dk = 8;      // input dim
constexpr int Kc = 16;     // output capsules
constexpr int En = 16;     // output dim
constexpr float EPS = 1e-7f;

// Decomposition
constexpr int NW   = 4;            // waves per block
constexpr int ICW  = 4;            // i's per wave
constexpr int IB   = NW * ICW;     // 16 i's per block
constexpr int P    = In / IB;      // 128 i-chunks
constexpr int BSET = 16;           // batches per block
constexpr int NBG  = Bn / BSET;    // 4 batch groups
constexpr int BLOCKS = P * NBG;    // 512 blocks (2/CU, fully co-resident)

// One routing iteration, atomic-free.
// Block (p,g): i-chunk of 16 i's x batch-group of 16 batches.
// u_hat recomputed on the fly from x (LDS) and W (registers, streamed from L2/L3).
// Lane l of a wave owns (k = l>>2, e4 = (l&3)*4): 4 output dims of one capsule.
// Cross-wave LDS reduction -> one plain store per element into partial[b][p][e].
// UNIFORM=true : c = 1 (1/16 folded into the reduce kernel's scale)
// UNIFORM=false: logits t[k] = dot_e(u_hat[k,:], vsum[b,k,:]); c = softmax_k(t)
//                (no max subtraction: |t| <= ~11, far from fp32 overflow)
template<bool UNIFORM>
__global__ __launch_bounds__(256)
void caps_iter(const float* __restrict__ x,     // [B, I, 8]
               const float* __restrict__ W,     // [I, K, 8, E]
               const float* __restrict__ vsum,  // [B, K, E]
               float* __restrict__ partial)     // [B, P, K*E]
{
    // Phase A: smem[0..2047] = x-stage (8 KB), smem[2048..6143] = vsum (16 KB)
    // Phase B: smem[wv*4096 .. +4095] = per-wave reduction slabs (64 KB total)
    __shared__ __align__(16) float smem[16384];

    const int t  = threadIdx.x;
    const int p  = blockIdx.x >> 2;         // i-chunk
    const int g  = blockIdx.x & 3;          // batch group
    const int b0 = g * BSET;
    const int i0 = p * IB;

    // ---- stage x[b0+bl][i0..i0+15][0..7] -> smem [bl][il][d] (512 float4) ----
    {
        const int bl = t >> 5;              // 0..7  (two passes cover 16 bl)
        const int r  = t & 31;              // float4 index within a bl-row
        const float4* src0 = (const float4*)(x + ((size_t)(b0 + bl) * In + i0) * Dk);
        const float4* src1 = (const float4*)(x + ((size_t)(b0 + bl + 8) * In + i0) * Dk);
        ((float4*)smem)[bl * 32 + r]        = src0[r];
        ((float4*)smem)[(bl + 8) * 32 + r]  = src1[r];
    }
    // ---- stage vsum[b0..b0+15][k][e] -> smem+2048 (1024 float4) ----
    if (!UNIFORM) {
        const float4* vsrc = (const float4*)(vsum + (size_t)b0 * (Kc * En));
        #pragma unroll
        for (int j = 0; j < 4; ++j)
            ((float4*)(smem + 2048))[t + j * 256] = vsrc[t + j * 256];
    }

    const int lane = t & 63;
    const int wv   = t >> 6;
    const int k    = lane >> 2;             // output capsule
    const int e4   = (lane & 3) << 2;       // first of 4 output dims

    __syncthreads();

    float4 acc[BSET];
    #pragma unroll
    for (int bl = 0; bl < BSET; ++bl) acc[bl] = make_float4(0.f, 0.f, 0.f, 0.f);

    #pragma unroll 2
    for (int ii = 0; ii < ICW; ++ii) {
        const int il = wv * ICW + ii;
        const int i  = i0 + il;
        // W[i, k, d, e4:e4+4] staged in registers (streams from L2/L3)
        const float* wp = W + (size_t)i * (Kc * Dk * En) + k * (Dk * En) + e4;
        float4 w[8];
        #pragma unroll
        for (int d = 0; d < 8; ++d) w[d] = *(const float4*)(wp + d * En);

        #pragma unroll
        for (int bl = 0; bl < BSET; ++bl) {
            const float* xp = smem + ((bl * IB + il) << 3);   // broadcast reads
            const float4 x0 = *(const float4*)xp;
            const float4 x1 = *(const float4*)(xp + 4);
            const float xs8[8] = {x0.x, x0.y, x0.z, x0.w, x1.x, x1.y, x1.z, x1.w};

            float4 uh = make_float4(0.f, 0.f, 0.f, 0.f);
            #pragma unroll
            for (int d = 0; d < 8; ++d) {
                uh.x = fmaf(xs8[d], w[d].x, uh.x);
                uh.y = fmaf(xs8[d], w[d].y, uh.y);
                uh.z = fmaf(xs8[d], w[d].z, uh.z);
                uh.w = fmaf(xs8[d], w[d].w, uh.w);
            }

            if (UNIFORM) {
                acc[bl].x += uh.x; acc[bl].y += uh.y;
                acc[bl].z += uh.z; acc[bl].w += uh.w;
            } else {
                const float4 vb = *(const float4*)(smem + 2048 + (bl << 8) + k * 16 + e4);
                float tt = uh.x * vb.x + uh.y * vb.y + uh.z * vb.z + uh.w * vb.w;
                tt += __shfl_xor(tt, 1);          // reduce over e (lane bits 0..1)
                tt += __shfl_xor(tt, 2);
                const float pe = __expf(tt);      // no max-sub: |tt| small
                float den = pe;                    // softmax denom over k (bits 2..5)
                den += __shfl_xor(den, 4);
                den += __shfl_xor(den, 8);
                den += __shfl_xor(den, 16);
                den += __shfl_xor(den, 32);
                const float c = pe * __builtin_amdgcn_rcpf(den);
                acc[bl].x = fmaf(c, uh.x, acc[bl].x);
                acc[bl].y = fmaf(c, uh.y, acc[bl].y);
                acc[bl].z = fmaf(c, uh.z, acc[bl].z);
                acc[bl].w = fmaf(c, uh.w, acc[bl].w);
            }
        }
    }

    // ---- cross-wave LDS reduction, then one plain store per element ----
    __syncthreads();                                  // x/vsum stages dead now
    {
        float* slab = smem + (wv << 12);              // [wv][bl][256]
        #pragma unroll
        for (int bl = 0; bl < BSET; ++bl)
            *(float4*)(slab + (bl << 8) + k * 16 + e4) = acc[bl];
    }
    __syncthreads();
    #pragma unroll
    for (int bl = 0; bl < BSET; ++bl) {
        const int idx = (bl << 8) + t;
        const float s = smem[idx] + smem[4096 + idx] + smem[8192 + idx] + smem[12288 + idx];
        partial[((size_t)(b0 + bl) * P + p) * 256 + t] = s;
    }
}

// Sum the P partials (contiguous stream per b), then v = squash(scale*s) [+ vprev].
// Grid: 256 blocks = (b, quarter), 64 threads.
__global__ __launch_bounds__(64)
void caps_reduce(const float* __restrict__ partial, float scale,
                 const float* __restrict__ vprev, float* __restrict__ vout)
{
    const int b  = blockIdx.x >> 2;
    const int q  = blockIdx.x & 3;
    const int t  = threadIdx.x;
    const int el = (q << 6) + t;            // (k,e) element 0..255
    const float* pp = partial + (size_t)b * P * 256 + el;

    float s[8];
    #pragma unroll
    for (int j = 0; j < 8; ++j) s[j] = 0.f;
    #pragma unroll 2
    for (int p0 = 0; p0 < P; p0 += 8) {
        #pragma unroll
        for (int j = 0; j < 8; ++j) s[j] += pp[(size_t)(p0 + j) * 256];
    }
    const float val = (((s[0]+s[1])+(s[2]+s[3])) + ((s[4]+s[5])+(s[6]+s[7]))) * scale;

    float sq = val * val;                   // e = el & 15 == t & 15
    sq += __shfl_xor(sq, 1);
    sq += __shfl_xor(sq, 2);
    sq += __shfl_xor(sq, 4);
    sq += __shfl_xor(sq, 8);
    const float f = sq / ((1.0f + sq) * sqrtf(sq + EPS));
    float v = val * f;
    if (vprev) v += vprev[(b << 8) + el];
    vout[(b << 8) + el] = v;
}

extern "C" void kernel_launch(void* const* d_in, const int* in_sizes, int n_in,
                              void* d_out, int out_size, void* d_ws, size_t ws_size,
                              hipStream_t stream) {
    const float* x = (const float*)d_in[0];   // [64, 2048, 8]
    const float* W = (const float*)d_in[1];   // [2048, 16, 8, 16]
    float* out = (float*)d_out;               // [64, 16, 16]
    float* ws  = (float*)d_ws;

    float* v0      = ws;                      // [64,16,16]
    float* vs      = ws + 16384;              // v0 + v1
    float* partial = ws + 32768;              // [64][128][256] = 8 MB

    dim3 iblk(256), igrid(BLOCKS);
    dim3 rblk(64),  rgrid(256);

    // r = 0: uniform coupling (1/16 folded into reduce scale)
    caps_iter<true ><<<igrid, iblk, 0, stream>>>(x, W, nullptr, partial);
    caps_reduce<<<rgrid, rblk, 0, stream>>>(partial, 1.0f / 16.0f, nullptr, v0);

    // r = 1: logits = dot(u_hat, v0);  vs = v0 + v1
    caps_iter<false><<<igrid, iblk, 0, stream>>>(x, W, v0, partial);
    caps_reduce<<<rgrid, rblk, 0, stream>>>(partial, 1.0f, v0, vs);

    // r = 2: logits = dot(u_hat, v0 + v1)
    caps_iter<false><<<igrid, iblk, 0, stream>>>(x, W, vs, partial);
    caps_reduce<<<rgrid, rblk, 0, stream>>>(partial, 1.0f, nullptr, out);
}